// Round 7
// baseline (55.215 us; speedup 1.0000x reference)
//
#include <hip/hip_runtime.h>
#include <math.h>

#define EPS_F 1e-8f

__device__ __forceinline__ float rcp_fast(float x) { return __builtin_amdgcn_rcpf(x); }

__launch_bounds__(256)
__global__ void iou3d_fused_kernel(const float* __restrict__ g,
                                   const float* __restrict__ q,
                                   float* __restrict__ out,
                                   float* __restrict__ partial,
                                   unsigned* __restrict__ counter,
                                   int n, int nblocks, float invn) {
    // coalesced staging: 256 boxes x 7 floats per array, loaded as float4
    __shared__ float sgb[1792];
    __shared__ float sqb[1792];
    const int tid = threadIdx.x;
    const size_t elemBase = (size_t)blockIdx.x * (256 * 7);
    const long long availll = (long long)n * 7 - (long long)elemBase;
    const int avail = (availll > 1792) ? 1792 : (int)availll;
    const int avail4 = avail >> 2;
    const float4* g4 = (const float4*)(g + elemBase);
    const float4* q4 = (const float4*)(q + elemBase);
#pragma unroll 2
    for (int i = tid; i < avail4; i += 256) {
        ((float4*)sgb)[i] = g4[i];
        ((float4*)sqb)[i] = q4[i];
    }
    for (int i = (avail4 << 2) + tid; i < avail; i += 256) {
        sgb[i] = g[elemBase + i];
        sqb[i] = q[elemBase + i];
    }
    __syncthreads();

    const int gid = blockIdx.x * 256 + tid;
    float loss = 0.0f;
    if (gid < n) {
        const float* gb = sgb + tid * 7;
        const float* qb = sqb + tid * 7;
        const float gx = gb[0], gy = gb[1], gz = gb[2], gh = gb[3], gw = gb[4], gl = gb[5], gr = gb[6];
        const float qx = qb[0], qy = qb[1], qz = qb[2], qh = qb[3], qw = qb[4], ql = qb[5], qr = qb[6];

        float sg, cg, sq_, cq;
        __sincosf(gr, &sg, &cg);
        __sincosf(qr, &sq_, &cq);

        // BEV corners relative to (gx, gz); reference corner order is CW.
        const float LX[4] = {0.5f, 0.5f, -0.5f, -0.5f};
        const float LZ[4] = {0.5f, -0.5f, -0.5f, 0.5f};
        const float dqx = qx - gx, dqz = qz - gz;
        float ax[4], az[4], bx[4], bz[4];
#pragma unroll
        for (int k = 0; k < 4; ++k) {
            const float cxg = LX[k] * gl, czg = LZ[k] * gw;
            ax[k] =  cg * cxg + sg * czg;
            az[k] = -sg * cxg + cg * czg;
            const float cxq = LX[k] * ql, czq = LZ[k] * qw;
            bx[k] =  cq * cxq + sq_ * czq + dqx;
            bz[k] = -sq_ * cxq + cq * czq + dqz;
        }

        float aex[4], aez[4], acc_[4], bex[4], bez[4], bcc[4];
#pragma unroll
        for (int k = 0; k < 4; ++k) {
            aex[k] = ax[(k + 1) & 3] - ax[k];
            aez[k] = az[(k + 1) & 3] - az[k];
            acc_[k] = aex[k] * az[k] - aez[k] * ax[k];
            bex[k] = bx[(k + 1) & 3] - bx[k];
            bez[k] = bz[(k + 1) & 3] - bz[k];
            bcc[k] = bex[k] * bz[k] - bez[k] * bx[k];
        }

        // shared edge-direction crosses + reciprocals (B-loop reuses with sign flips)
        float sm[4][4], rr[4][4];
#pragma unroll
        for (int k = 0; k < 4; ++k)
#pragma unroll
            for (int h = 0; h < 4; ++h) {
                sm[k][h] = bex[h] * aez[k] - bez[h] * aex[k];
                rr[k][h] = rcp_fast(sm[k][h]);
            }

        // Green's theorem: 2*Area = |Σ clipped-segment (t1-t0)*cross(P,d)|
        float total = 0.0f;

        // A edges clipped by B. Parallel-outside (s==+0, f0>0) is subsumed:
        // tt = -f0*rcp(+0) = -inf -> t1 = -inf -> rejected; f0==0 -> tt=NaN,
        // fminf ignores NaN (v_min_f32 minNum semantics).
#pragma unroll
        for (int k = 0; k < 4; ++k) {
            const float Px = ax[k], Pz = az[k];
            float t0 = 0.0f, t1 = 1.0f;
#pragma unroll
            for (int h = 0; h < 4; ++h) {
                const float s  = sm[k][h];
                const float f0 = bex[h] * Pz - bez[h] * Px - bcc[h];
                const float tt = -f0 * rr[k][h];
                const float c1 = (s >= 0.0f) ? tt : 1e30f;
                const float c0 = (s >= 0.0f) ? -1e30f : tt;
                t1 = fminf(t1, c1);
                t0 = fmaxf(t0, c0);
            }
            total += fmaxf(t1 - t0, 0.0f) * (-acc_[k]);
        }
        // B edges clipped by A (s' = -sm, tt = f0*rr; explicit parallel handling —
        // the rcp(±0) sign trick is unsafe under negation)
#pragma unroll
        for (int h = 0; h < 4; ++h) {
            const float Px = bx[h], Pz = bz[h];
            float t0 = 0.0f, t1 = 1.0f;
#pragma unroll
            for (int k = 0; k < 4; ++k) {
                const float s  = -sm[k][h];
                const float f0 = aex[k] * Pz - aez[k] * Px - acc_[k];
                const float tt = f0 * rr[k][h];
                t1 = (s > 0.0f) ? fminf(t1, tt) : t1;
                t0 = (s < 0.0f) ? fmaxf(t0, tt) : t0;
                t0 = ((s == 0.0f) && (f0 > 0.0f)) ? 1e9f : t0;
            }
            total += fmaxf(t1 - t0, 0.0f) * (-bcc[h]);
        }

        const float area = 0.5f * fabsf(total);

        const float hov = fmaxf(fminf(gy, qy) - fmaxf(gy - gh, qy - qh), 0.0f);
        const float inter = area * hov;
        const float va = gh * gw * gl;
        const float vb = qh * qw * ql;
        float iou = inter / (va + vb - inter + EPS_F);
        iou = fminf(fmaxf(iou, 0.0f), 1.0f);
        loss = 1.0f - iou;
    }

    // deterministic block reduction: wave shfl (width 64) + LDS
#pragma unroll
    for (int off = 32; off > 0; off >>= 1) loss += __shfl_down(loss, off, 64);
    __shared__ float wsum[4];
    __shared__ bool amLast;
    const int lane = tid & 63;
    const int wid = tid >> 6;
    if (lane == 0) wsum[wid] = loss;
    __syncthreads();
    if (tid == 0) {
        partial[blockIdx.x] = wsum[0] + wsum[1] + wsum[2] + wsum[3];
        __threadfence();                                   // release: L2 writeback (cross-XCD)
        const unsigned t = atomicAdd(counter, 1u);         // device-scope ticket
        amLast = (t == (unsigned)(nblocks - 1));
    }
    __syncthreads();

    if (amLast) {
        __threadfence();                                   // acquire: invalidate stale caches
        // fixed-order final sum: thread t sums k = t, t+256, ... -> deterministic
        float s = 0.f;
        for (int k = tid; k < nblocks; k += 256) s += partial[k];
#pragma unroll
        for (int off = 32; off > 0; off >>= 1) s += __shfl_down(s, off, 64);
        if (lane == 0) wsum[wid] = s;
        __syncthreads();
        if (tid == 0) out[0] = (wsum[0] + wsum[1] + wsum[2] + wsum[3]) * invn;
    }
}

extern "C" void kernel_launch(void* const* d_in, const int* in_sizes, int n_in,
                              void* d_out, int out_size, void* d_ws, size_t ws_size,
                              hipStream_t stream) {
    const float* g = (const float*)d_in[0];
    const float* q = (const float*)d_in[1];
    float* out = (float*)d_out;
    const int n = in_sizes[0] / 7;
    const int block = 256;
    const int nblocks = (n + block - 1) / block;          // 2048 for N=524288
    unsigned* counter = (unsigned*)d_ws;                  // 4-byte ticket at ws[0]
    float* partial = (float*)((char*)d_ws + 256);         // partials after a pad
    hipMemsetAsync(counter, 0, 4, stream);                // reset ticket every call (graph-legal)
    iou3d_fused_kernel<<<nblocks, block, 0, stream>>>(g, q, out, partial, counter,
                                                      n, nblocks, 1.0f / (float)n);
}

// Round 8
// 39.283 us; speedup vs baseline: 1.4056x; 1.4056x over previous
//
#include <hip/hip_runtime.h>
#include <math.h>

#define EPS_F 1e-8f

__device__ __forceinline__ float rcp_fast(float x) { return __builtin_amdgcn_rcpf(x); }

__launch_bounds__(256)
__global__ void iou3d_fused_kernel(const float* __restrict__ g,
                                   const float* __restrict__ q,
                                   float* __restrict__ out,
                                   float* __restrict__ partial,
                                   unsigned* __restrict__ counter,
                                   int n, int nblocks, float invn) {
    // coalesced staging: 256 boxes x 7 floats per array, loaded as float4
    __shared__ float sgb[1792];
    __shared__ float sqb[1792];
    const int tid = threadIdx.x;
    const size_t elemBase = (size_t)blockIdx.x * (256 * 7);
    const long long availll = (long long)n * 7 - (long long)elemBase;
    const int avail = (availll > 1792) ? 1792 : (int)availll;
    const int avail4 = avail >> 2;
    const float4* g4 = (const float4*)(g + elemBase);
    const float4* q4 = (const float4*)(q + elemBase);
#pragma unroll 2
    for (int i = tid; i < avail4; i += 256) {
        ((float4*)sgb)[i] = g4[i];
        ((float4*)sqb)[i] = q4[i];
    }
    for (int i = (avail4 << 2) + tid; i < avail; i += 256) {
        sgb[i] = g[elemBase + i];
        sqb[i] = q[elemBase + i];
    }
    __syncthreads();

    const int gid = blockIdx.x * 256 + tid;
    float loss = 0.0f;
    if (gid < n) {
        const float* gb = sgb + tid * 7;
        const float* qb = sqb + tid * 7;
        const float gx = gb[0], gy = gb[1], gz = gb[2], gh = gb[3], gw = gb[4], gl = gb[5], gr = gb[6];
        const float qx = qb[0], qy = qb[1], qz = qb[2], qh = qb[3], qw = qb[4], ql = qb[5], qr = qb[6];

        float sg, cg, sq_, cq;
        __sincosf(gr, &sg, &cg);
        __sincosf(qr, &sq_, &cq);

        // BEV corners relative to (gx, gz); reference corner order is CW.
        const float LX[4] = {0.5f, 0.5f, -0.5f, -0.5f};
        const float LZ[4] = {0.5f, -0.5f, -0.5f, 0.5f};
        const float dqx = qx - gx, dqz = qz - gz;
        float ax[4], az[4], bx[4], bz[4];
#pragma unroll
        for (int k = 0; k < 4; ++k) {
            const float cxg = LX[k] * gl, czg = LZ[k] * gw;
            ax[k] =  cg * cxg + sg * czg;
            az[k] = -sg * cxg + cg * czg;
            const float cxq = LX[k] * ql, czq = LZ[k] * qw;
            bx[k] =  cq * cxq + sq_ * czq + dqx;
            bz[k] = -sq_ * cxq + cq * czq + dqz;
        }

        float aex[4], aez[4], acc_[4], bex[4], bez[4], bcc[4];
#pragma unroll
        for (int k = 0; k < 4; ++k) {
            aex[k] = ax[(k + 1) & 3] - ax[k];
            aez[k] = az[(k + 1) & 3] - az[k];
            acc_[k] = aex[k] * az[k] - aez[k] * ax[k];
            bex[k] = bx[(k + 1) & 3] - bx[k];
            bez[k] = bz[(k + 1) & 3] - bz[k];
            bcc[k] = bex[k] * bz[k] - bez[k] * bx[k];
        }

        // shared edge-direction crosses + reciprocals (B-loop reuses with sign flips)
        float sm[4][4], rr[4][4];
#pragma unroll
        for (int k = 0; k < 4; ++k)
#pragma unroll
            for (int h = 0; h < 4; ++h) {
                sm[k][h] = bex[h] * aez[k] - bez[h] * aex[k];
                rr[k][h] = rcp_fast(sm[k][h]);
            }

        // Green's theorem: 2*Area = |Σ clipped-segment (t1-t0)*cross(P,d)|
        float total = 0.0f;

        // A edges clipped by B. Parallel-outside (s==+0, f0>0) subsumed by
        // tt = -f0*rcp(+0) = -inf -> t1 = -inf; f0==0 -> NaN ignored by fminf.
#pragma unroll
        for (int k = 0; k < 4; ++k) {
            const float Px = ax[k], Pz = az[k];
            float t0 = 0.0f, t1 = 1.0f;
#pragma unroll
            for (int h = 0; h < 4; ++h) {
                const float s  = sm[k][h];
                const float f0 = bex[h] * Pz - bez[h] * Px - bcc[h];
                const float tt = -f0 * rr[k][h];
                const float c1 = (s >= 0.0f) ? tt : 1e30f;
                const float c0 = (s >= 0.0f) ? -1e30f : tt;
                t1 = fminf(t1, c1);
                t0 = fmaxf(t0, c0);
            }
            total += fmaxf(t1 - t0, 0.0f) * (-acc_[k]);
        }
        // B edges clipped by A (s' = -sm, tt = f0*rr; explicit parallel handling)
#pragma unroll
        for (int h = 0; h < 4; ++h) {
            const float Px = bx[h], Pz = bz[h];
            float t0 = 0.0f, t1 = 1.0f;
#pragma unroll
            for (int k = 0; k < 4; ++k) {
                const float s  = -sm[k][h];
                const float f0 = aex[k] * Pz - aez[k] * Px - acc_[k];
                const float tt = f0 * rr[k][h];
                t1 = (s > 0.0f) ? fminf(t1, tt) : t1;
                t0 = (s < 0.0f) ? fmaxf(t0, tt) : t0;
                t0 = ((s == 0.0f) && (f0 > 0.0f)) ? 1e9f : t0;
            }
            total += fmaxf(t1 - t0, 0.0f) * (-bcc[h]);
        }

        const float area = 0.5f * fabsf(total);

        const float hov = fmaxf(fminf(gy, qy) - fmaxf(gy - gh, qy - qh), 0.0f);
        const float inter = area * hov;
        const float va = gh * gw * gl;
        const float vb = qh * qw * ql;
        float iou = inter / (va + vb - inter + EPS_F);
        iou = fminf(fmaxf(iou, 0.0f), 1.0f);
        loss = 1.0f - iou;
    }

    // deterministic block reduction: wave shfl (width 64) + LDS
#pragma unroll
    for (int off = 32; off > 0; off >>= 1) loss += __shfl_down(loss, off, 64);
    __shared__ float wsum[4];
    __shared__ bool amLast;
    const int lane = tid & 63;
    const int wid = tid >> 6;
    if (lane == 0) wsum[wid] = loss;
    __syncthreads();
    if (tid == 0) {
        // coherent-point store (agent-scope atomic: sc0/sc1 bypass, NO L2 writeback)
        __hip_atomic_store(&partial[blockIdx.x], wsum[0] + wsum[1] + wsum[2] + wsum[3],
                           __ATOMIC_RELAXED, __HIP_MEMORY_SCOPE_AGENT);
        // order: partial ack'd at coherent point before the ticket increments
        asm volatile("s_waitcnt vmcnt(0)" ::: "memory");
        const unsigned t = __hip_atomic_fetch_add(counter, 1u,
                           __ATOMIC_RELAXED, __HIP_MEMORY_SCOPE_AGENT);
        amLast = (t == (unsigned)(nblocks - 1));
    }
    __syncthreads();

    if (amLast) {
        // fixed-order final sum via coherent loads -> deterministic
        float s = 0.f;
        for (int k = tid; k < nblocks; k += 256)
            s += __hip_atomic_load(&partial[k], __ATOMIC_RELAXED, __HIP_MEMORY_SCOPE_AGENT);
#pragma unroll
        for (int off = 32; off > 0; off >>= 1) s += __shfl_down(s, off, 64);
        if (lane == 0) wsum[wid] = s;
        __syncthreads();
        if (tid == 0) out[0] = (wsum[0] + wsum[1] + wsum[2] + wsum[3]) * invn;
    }
}

extern "C" void kernel_launch(void* const* d_in, const int* in_sizes, int n_in,
                              void* d_out, int out_size, void* d_ws, size_t ws_size,
                              hipStream_t stream) {
    const float* g = (const float*)d_in[0];
    const float* q = (const float*)d_in[1];
    float* out = (float*)d_out;
    const int n = in_sizes[0] / 7;
    const int block = 256;
    const int nblocks = (n + block - 1) / block;          // 2048 for N=524288
    unsigned* counter = (unsigned*)d_ws;                  // 4-byte ticket at ws[0]
    float* partial = (float*)((char*)d_ws + 256);         // partials after a pad
    hipMemsetAsync(counter, 0, 4, stream);                // reset ticket each call (graph-legal)
    iou3d_fused_kernel<<<nblocks, block, 0, stream>>>(g, q, out, partial, counter,
                                                      n, nblocks, 1.0f / (float)n);
}